// Round 4
// baseline (279.237 us; speedup 1.0000x reference)
//
#include <hip/hip_runtime.h>
#include <hip/hip_bf16.h>

// Problem constants: B,L,M,D,K,STRIDE = 32,32768,32,128,16,8
#define Bn 32
#define Ln 32768
#define Mn 32
#define Dn 128
#define Pn 4095            // (L - K)/STRIDE + 1
#define KKn 512            // M*K  (GEMM reduction dim)

typedef short  bf16x8 __attribute__((ext_vector_type(8)));  // 8 bf16 = 4 VGPRs
typedef float  f32x4  __attribute__((ext_vector_type(4)));

union BU { bf16x8 v; unsigned short u[8]; };

static __device__ __forceinline__ unsigned short f2bf(float f) {
  __hip_bfloat16 h = __float2bfloat16(f);
  return *reinterpret_cast<unsigned short*>(&h);
}

static __device__ __forceinline__ bf16x8 cvt8(const float4& a, const float4& b) {
  BU bu;
  bu.u[0] = f2bf(a.x); bu.u[1] = f2bf(a.y); bu.u[2] = f2bf(a.z); bu.u[3] = f2bf(a.w);
  bu.u[4] = f2bf(b.x); bu.u[5] = f2bf(b.y); bu.u[6] = f2bf(b.z); bu.u[7] = f2bf(b.w);
  return bu.v;
}

// ---------------------------------------------------------------------------
// Prep: conv_w (D,M,K) fp32 -> fragment-ready bf16 table in d_ws (16 KB-ish).
// kk = k*32 + m; B-frag lane d, kk = t*32 + quad*8 + j
//   -> wswz[((kk>>3)*128 + d)*8 + (kk&7)]  (one 16-B load per fragment)
// ---------------------------------------------------------------------------
__global__ __launch_bounds__(256) void prep_w_kernel(const float* __restrict__ w,
                                                     unsigned short* __restrict__ wswz) {
  int idx = blockIdx.x * 256 + threadIdx.x;   // 0..65535
  int j = idx & 7;
  int d = (idx >> 3) & 127;
  int g = idx >> 10;
  int kk = g * 8 + j;
  int k = kk >> 5;
  int m = kk & 31;
  wswz[idx] = f2bf(w[(d << 9) + (m << 4) + k]);   // w[d][m][k]
}

// ---------------------------------------------------------------------------
// Main: LDS-free, barrier-free. Block = 64 patches x 128 d, 4 waves.
// Wave (wp = wv&1, wd = wv>>1) owns 32 patches (2 pt-tiles) x 64 d (4 dt).
// A-fragments stream straight from global (L1/L2-cached; per-t working set
// 8 KB << L1); explicit 2-stage register double buffer; B from 16 KB L1-hot
// table with depth-2 prefetch.  No LDS => occupancy is VGPR-bound only.
// ---------------------------------------------------------------------------
__global__ __launch_bounds__(256, 3) void gemm_pe_kernel(
    const float* __restrict__ x,          // (B, L, M) fp32
    const float* __restrict__ ts,         // (B, L)    fp32, sorted along L
    const unsigned short* __restrict__ wswz,
    const float* __restrict__ bias,       // (D,)
    float* __restrict__ out) {            // (B, P, D) fp32

  const int b   = blockIdx.y;
  const int pt0 = blockIdx.x;             // 64-patch tile id, 0..63
  const int tid = threadIdx.x;
  const int lane = tid & 63;
  const int wv   = tid >> 6;
  const int mrow = lane & 15;
  const int quad = lane >> 4;
  const int wp = wv & 1;                  // patch half (32 patches)
  const int wd = wv >> 1;                 // d half (64 d)

  // A base pointers: element addr = p*256 + t*32 + quad*8 floats.
  // All 16 K-steps use immediate offsets t*128(+16) bytes off these bases.
  const float* xb = x + (size_t)b * (Ln * Mn);
  const float* ap[2];
  #pragma unroll
  for (int pt = 0; pt < 2; ++pt) {
    int p = pt0 * 64 + wp * 32 + pt * 16 + mrow;
    int pc = (p < Pn) ? p : 0;            // clamp p=4095 lane (rows never stored)
    ap[pt] = xb + (size_t)pc * 256 + quad * 8;
  }
  // B table base for this lane: ((quad*128 + wd*64 + mrow)*8); dt adds 128
  // shorts (256 B imm), t adds 4096 shorts (pointer bump).
  const unsigned short* bq = wswz + (((quad << 7) + (wd << 6) + mrow) << 3);

  // ---- preload: A stage 0, B ring depth 2 ----
  float4 ar[2][2][2];                     // [stage][pt][half]  = 32 VGPRs
  #pragma unroll
  for (int pt = 0; pt < 2; ++pt) {
    ar[0][pt][0] = *reinterpret_cast<const float4*>(ap[pt]);
    ar[0][pt][1] = *reinterpret_cast<const float4*>(ap[pt] + 4);
  }
  bf16x8 bp[2][4];                        // 32 VGPRs
  #pragma unroll
  for (int dt = 0; dt < 4; ++dt)
    bp[0][dt] = *reinterpret_cast<const bf16x8*>(bq + dt * 128);
  #pragma unroll
  for (int dt = 0; dt < 4; ++dt)
    bp[1][dt] = *reinterpret_cast<const bf16x8*>(bq + 4096 + dt * 128);
  bq += 8192;

  f32x4 acc[2][4] = {};                   // 32 VGPRs

  #pragma unroll
  for (int t = 0; t < 16; ++t) {
    const int cur = t & 1, nxt = cur ^ 1;
    // prefetch A for t+1 (imm offsets, no addr arithmetic)
    if (t < 15) {
      #pragma unroll
      for (int pt = 0; pt < 2; ++pt) {
        ar[nxt][pt][0] = *reinterpret_cast<const float4*>(ap[pt] + (t + 1) * 32);
        ar[nxt][pt][1] = *reinterpret_cast<const float4*>(ap[pt] + (t + 1) * 32 + 4);
      }
    }
    // consume current B, prefetch t+2
    bf16x8 bc[4];
    #pragma unroll
    for (int dt = 0; dt < 4; ++dt) bc[dt] = bp[cur][dt];
    if (t < 14) {
      #pragma unroll
      for (int dt = 0; dt < 4; ++dt)
        bp[cur][dt] = *reinterpret_cast<const bf16x8*>(bq + dt * 128);
      bq += 4096;
    }
    // convert current A and MFMA
    bf16x8 af[2];
    #pragma unroll
    for (int pt = 0; pt < 2; ++pt) af[pt] = cvt8(ar[cur][pt][0], ar[cur][pt][1]);
    #pragma unroll
    for (int pt = 0; pt < 2; ++pt)
      #pragma unroll
      for (int dt = 0; dt < 4; ++dt)
        acc[pt][dt] = __builtin_amdgcn_mfma_f32_16x16x32_bf16(
            af[pt], bc[dt], acc[pt][dt], 0, 0, 0);
  }

  // ---- epilogue: + bias + PE.  C/D: col(lane&15)=d, row(quad*4+reg)=p ----
  const int d0 = wd * 64 + mrow;
  const float NEG_C = -0.14391156831212810f;            // -ln(10000)/64
  float div4[4], bias4[4];
  #pragma unroll
  for (int dt = 0; dt < 4; ++dt) {
    div4[dt]  = __expf(NEG_C * (float)((d0 + dt * 16) >> 1));
    bias4[dt] = bias[d0 + dt * 16];
  }
  const float phs = (d0 & 1) ? 1.5707963267948966f : 0.0f;
  const float* tsb = ts + (size_t)b * Ln;

  #pragma unroll
  for (int pt = 0; pt < 2; ++pt) {
    const int pbase = pt0 * 64 + wp * 32 + pt * 16 + quad * 4;
    float* ob = out + ((size_t)b * Pn + pbase) * Dn + d0;
    float med[4];
    #pragma unroll
    for (int reg = 0; reg < 4; ++reg)
      med[reg] = tsb[(pbase + reg) * 8 + 7];   // p<=4095 -> idx<=32767, in bounds
    #pragma unroll
    for (int reg = 0; reg < 4; ++reg) {
      if (pbase + reg < Pn) {
        #pragma unroll
        for (int dt = 0; dt < 4; ++dt) {
          float pe = __sinf(med[reg] * div4[dt] + phs);
          ob[reg * Dn + dt * 16] = acc[pt][dt][reg] + bias4[dt] + pe;
        }
      }
    }
  }
}

extern "C" void kernel_launch(void* const* d_in, const int* in_sizes, int n_in,
                              void* d_out, int out_size, void* d_ws, size_t ws_size,
                              hipStream_t stream) {
  const float* x      = (const float*)d_in[0];   // (32, 32768, 32)
  const float* ts     = (const float*)d_in[1];   // (32, 32768)
  const float* conv_w = (const float*)d_in[2];   // (128, 32, 16)
  const float* conv_b = (const float*)d_in[3];   // (128,)
  float* out = (float*)d_out;
  unsigned short* wswz = (unsigned short*)d_ws;  // 512*128 bf16 = 128 KiB

  prep_w_kernel<<<256, 256, 0, stream>>>(conv_w, wswz);
  gemm_pe_kernel<<<dim3(64, Bn), 256, 0, stream>>>(x, ts, wswz, conv_b, out);
}

// Round 6
// 229.185 us; speedup vs baseline: 1.2184x; 1.2184x over previous
//
#include <hip/hip_runtime.h>
#include <hip/hip_bf16.h>

// Problem constants: B,L,M,D,K,STRIDE = 32,32768,32,128,16,8
#define Bn 32
#define Ln 32768
#define Mn 32
#define Dn 128
#define Pn 4095            // (L - K)/STRIDE + 1
#define KKn 512            // M*K  (GEMM reduction dim)

typedef short  bf16x8 __attribute__((ext_vector_type(8)));  // 8 bf16 = 4 VGPRs
typedef float  f32x4  __attribute__((ext_vector_type(4)));
typedef __attribute__((address_space(3))) unsigned int       lds_u32;
typedef const __attribute__((address_space(1))) unsigned int glb_u32;

union BU { bf16x8 v; unsigned short u[8]; };

static __device__ __forceinline__ unsigned short f2bf(float f) {
  __hip_bfloat16 h = __float2bfloat16(f);
  return *reinterpret_cast<unsigned short*>(&h);
}

static __device__ __forceinline__ bf16x8 cvt8(const f32x4& a, const f32x4& b) {
  BU bu;
  bu.u[0] = f2bf(a[0]); bu.u[1] = f2bf(a[1]); bu.u[2] = f2bf(a[2]); bu.u[3] = f2bf(a[3]);
  bu.u[4] = f2bf(b[0]); bu.u[5] = f2bf(b[1]); bu.u[6] = f2bf(b[2]); bu.u[7] = f2bf(b[3]);
  return bu.v;
}

// Involution on 16-B granule index: XOR low-3 (position-in-row) with the
// patch-row bits (bits 6-8).  Mask is invariant within a row, so the 8-float
// A-fragment's two granules map to phys gl and gl^1 for EVERY t (the round-5
// bug was a t-dependent mask bit).  mrow spreads reads across all 8 bank
// groups -> conflicts at the rounds-1-3 measured-benign level.
static __device__ __forceinline__ int phi(int g) {
  return g ^ ((g >> 6) & 7);
}

// ---------------------------------------------------------------------------
// Prep: conv_w (D,M,K) fp32 -> fragment-ready bf16 table in d_ws (128 KiB).
// kk = k*32 + m; B-frag lane d, kk = t*32 + quad*8 + j
//   -> wswz[((kk>>3)*128 + d)*8 + (kk&7)]  (one 16-B load per fragment)
// ---------------------------------------------------------------------------
__global__ __launch_bounds__(256) void prep_w_kernel(const float* __restrict__ w,
                                                     unsigned short* __restrict__ wswz) {
  int idx = blockIdx.x * 256 + threadIdx.x;   // 0..65535
  int j = idx & 7;
  int d = (idx >> 3) & 127;
  int g = idx >> 10;
  int kk = g * 8 + j;
  int k = kk >> 5;
  int m = kk & 31;
  wswz[idx] = f2bf(w[(d << 9) + (m << 4) + k]);   // w[d][m][k]
}

// ---------------------------------------------------------------------------
// Main (m97 skeleton): 32 patches x 128 d per block, 4 waves split by d.
// x slab staged fp32 -> LDS via global_load_lds DMA (zero VGPR round-trip, so
// the register allocator cannot re-serialize the staging — the failure mode
// of rounds 2-4).  LDS[phi(P)] = slab[P] via per-lane gather source phi(P).
// ---------------------------------------------------------------------------
__global__ __launch_bounds__(256, 4) void gemm_pe_kernel(
    const float* __restrict__ x,          // (B, L, M) fp32
    const float* __restrict__ ts,         // (B, L)    fp32, sorted along L
    const unsigned short* __restrict__ wswz,
    const float* __restrict__ bias,       // (D,)
    float* __restrict__ out) {            // (B, P, D) fp32

  __shared__ float xsf[9216];             // 2304 granules = 36,864 B (288 rows)
  __shared__ float tsl[32];

  const int b    = blockIdx.y;
  const int tile = blockIdx.x;            // 32-patch tile, 0..127
  const int tid  = threadIdx.x;
  const int lane = tid & 63;
  const int wv   = tid >> 6;              // d-block 0..3
  const int mrow = lane & 15;
  const int quad = lane >> 4;

  // ---- ts medians (sorted ts -> median of 16-window = element 7) ----
  if (tid < 32)
    tsl[tid] = ts[(size_t)b * Ln + tile * 256 + tid * 8 + 7];

  // ---- stage x slab -> LDS via async DMA, 9 instrs/wave, zero VGPR use ----
  // slab = 2304 granules (16 B) at float offset b*L*M + tile*8192.  Granules
  // past 2111 are overstage (never read); clamp OOB sources into range.
  {
    const size_t slab0g = (((size_t)b * Ln * Mn) >> 2) + (size_t)tile * 2048;
    const size_t xg_max = (((size_t)Bn * Ln * Mn) >> 2) - 1;
    #pragma unroll
    for (int j = 0; j < 9; ++j) {
      const int Pw = wv * 576 + j * 64;         // wave-uniform LDS granule base
      const int P  = Pw + lane;                 // lane's LDS granule (base+lane*16)
      size_t gg = slab0g + (size_t)phi(P);      // per-lane gather source
      if (gg > xg_max) gg = xg_max;             // finite garbage, never consumed
      __builtin_amdgcn_global_load_lds((glb_u32*)(x + (gg << 2)),
                                       (lds_u32*)&xsf[(size_t)Pw << 2], 16, 0, 0);
    }
  }

  // ---- B-frag ring: issue initial loads before the barrier (overlap) ----
  const unsigned short* bq = wswz + (((quad << 7) + (wv << 5) + mrow) << 3);
  bf16x8 bp[3][2];
  #pragma unroll
  for (int j = 0; j < 3; ++j) {
    bp[j][0] = *reinterpret_cast<const bf16x8*>(bq + j * 4096);
    bp[j][1] = *reinterpret_cast<const bf16x8*>(bq + j * 4096 + 128);
  }

  __syncthreads();                        // compiler emits vmcnt(0) drain here

  // ---- K-loop: 16 steps of K=32 ----
  // A-frag (pt,t): slab floats (pt*16+mrow)*256 + t*32 + quad*8 .. +8
  //   logical granules G, G+1 with G = (pt*16+mrow)*64 + t*8 + quad*2 (even);
  //   physical: gl = phi(G), gh = gl^1 (same row => same mask => exact).
  int agbase[2];
  #pragma unroll
  for (int pt = 0; pt < 2; ++pt) agbase[pt] = (pt * 16 + mrow) * 64 + quad * 2;

  f32x4 acc[2][2] = {};

  #pragma unroll
  for (int t = 0; t < 16; ++t) {
    const int cur = t % 3;
    bf16x8 af[2];
    #pragma unroll
    for (int pt = 0; pt < 2; ++pt) {
      const int G  = agbase[pt] + t * 8;
      const int gl = phi(G);
      const int gh = gl ^ 1;
      f32x4 lo = *reinterpret_cast<const f32x4*>(&xsf[gl * 4]);
      f32x4 hi = *reinterpret_cast<const f32x4*>(&xsf[gh * 4]);
      af[pt] = cvt8(lo, hi);
    }
    bf16x8 bc0 = bp[cur][0], bc1 = bp[cur][1];
    if (t < 13) {
      bp[cur][0] = *reinterpret_cast<const bf16x8*>(bq + (t + 3) * 4096);
      bp[cur][1] = *reinterpret_cast<const bf16x8*>(bq + (t + 3) * 4096 + 128);
    }
    #pragma unroll
    for (int pt = 0; pt < 2; ++pt) {
      acc[pt][0] = __builtin_amdgcn_mfma_f32_16x16x32_bf16(af[pt], bc0, acc[pt][0], 0, 0, 0);
      acc[pt][1] = __builtin_amdgcn_mfma_f32_16x16x32_bf16(af[pt], bc1, acc[pt][1], 0, 0, 0);
    }
  }

  // ---- epilogue: + bias + PE.  C/D: col(mrow)=d, row(quad*4+reg)=patch ----
  const int d0 = wv * 32 + mrow;
  const float NEG_C = -0.14391156831212810f;            // -ln(10000)/64
  const float div0  = __expf(NEG_C * (float)(d0 >> 1));
  const float div1  = __expf(NEG_C * (float)((d0 + 16) >> 1));
  const float phs   = (d0 & 1) ? 1.5707963267948966f : 0.0f;
  const float bias0 = bias[d0];
  const float bias1 = bias[d0 + 16];

  #pragma unroll
  for (int pt = 0; pt < 2; ++pt) {
    const int plbase = pt * 16 + quad * 4;
    f32x4 med4 = *reinterpret_cast<const f32x4*>(&tsl[plbase]);
    const int pbase = tile * 32 + plbase;
    float* ob = out + ((size_t)b * Pn + pbase) * Dn + d0;
    #pragma unroll
    for (int reg = 0; reg < 4; ++reg) {
      if (pbase + reg < Pn) {
        float m = med4[reg];
        float pe0 = __sinf(m * div0 + phs);
        float pe1 = __sinf(m * div1 + phs);
        ob[reg * Dn]      = acc[pt][0][reg] + bias0 + pe0;
        ob[reg * Dn + 16] = acc[pt][1][reg] + bias1 + pe1;
      }
    }
  }
}

extern "C" void kernel_launch(void* const* d_in, const int* in_sizes, int n_in,
                              void* d_out, int out_size, void* d_ws, size_t ws_size,
                              hipStream_t stream) {
  const float* x      = (const float*)d_in[0];   // (32, 32768, 32)
  const float* ts     = (const float*)d_in[1];   // (32, 32768)
  const float* conv_w = (const float*)d_in[2];   // (128, 32, 16)
  const float* conv_b = (const float*)d_in[3];   // (128,)
  float* out = (float*)d_out;
  unsigned short* wswz = (unsigned short*)d_ws;  // 512*128 bf16 = 128 KiB

  prep_w_kernel<<<256, 256, 0, stream>>>(conv_w, wswz);
  gemm_pe_kernel<<<dim3(128, Bn), 256, 0, stream>>>(x, ts, wswz, conv_b, out);
}